// Round 7
// baseline (231.329 us; speedup 1.0000x reference)
//
#include <hip/hip_runtime.h>
#include <math.h>

#define SEQ 2048
#define EMB 1024
#define NH  16
#define HD  64

typedef __attribute__((ext_vector_type(8))) short short8;   // 8 bf16 = 4 VGPRs
typedef __attribute__((ext_vector_type(4))) float f32x4;    // MFMA acc

static const size_t XE = (size_t)2 * SEQ * EMB;  // 4,194,304 elems
static const size_t WE = (size_t)EMB * EMB;      // 1,048,576 elems

// RNE float -> bf16 bits (inputs finite)
static __device__ __forceinline__ short f2bf(float f) {
    unsigned u = __builtin_bit_cast(unsigned, f);
    u = u + 0x7fffu + ((u >> 16) & 1u);
    return (short)(u >> 16);
}

#if __has_builtin(__builtin_amdgcn_cvt_pk_bf16_f32)
typedef __attribute__((ext_vector_type(2))) __bf16 bf16x2;
static __device__ __forceinline__ unsigned pk2(float a, float b) {
    bf16x2 v = __builtin_amdgcn_cvt_pk_bf16_f32(a, b);
    return __builtin_bit_cast(unsigned, v);
}
#else
static __device__ __forceinline__ unsigned pk2(float a, float b) {
    return (unsigned)(unsigned short)f2bf(a) |
           ((unsigned)(unsigned short)f2bf(b) << 16);
}
#endif

static __device__ __forceinline__ short8 cvt8(float4 a, float4 b) {
    union { unsigned u[4]; short8 s; } r;
    r.u[0] = pk2(a.x, a.y); r.u[1] = pk2(a.z, a.w);
    r.u[2] = pk2(b.x, b.y); r.u[3] = pk2(b.z, b.w);
    return r.s;
}

// async global->LDS, 16B/lane; LDS dest = wave-uniform base + lane*16
static __device__ __forceinline__ void gload16(const void* g, void* l) {
    __builtin_amdgcn_global_load_lds(
        (const __attribute__((address_space(1))) void*)g,
        (__attribute__((address_space(3))) void*)l, 16, 0, 0);
}

// ---------------------------------------------------------------------------
// Convert the three weight matrices to bf16: dst = [Wq | Wk | Wv].
// ---------------------------------------------------------------------------
__global__ __launch_bounds__(256)
void cvt_w(const float* __restrict__ s0, const float* __restrict__ s1,
           const float* __restrict__ s2, short* __restrict__ d) {
    int id = blockIdx.x;                 // 0..1535
    int seg = id >> 9, off = id & 511;
    const float* s = (seg == 0) ? s0 : (seg == 1) ? s1 : s2;
    short* dd = d + (size_t)seg * WE;
    size_t i = (size_t)off * 256 + threadIdx.x;
    const float4* sp = (const float4*)s;
    float4 a = sp[2 * i], b = sp[2 * i + 1];
    *(short8*)(dd + i * 8) = cvt8(a, b);
}

// ---------------------------------------------------------------------------
// Projection GEMM. Big operand (X, fp32) staged via global_load_lds into
// fp32 LDS (XOR chunk swizzle), converted at fragment-read time. Small
// operand (W, bf16 pre-converted) staged m97-style. 128x128 tile, BK=32,
// single-barrier double-buffer, XCD swizzle. NEW: packed epilogue -- acc
// goes through an LDS transpose (stride-136 shorts, <=2-way banks) and out
// as coalesced dwordx4 stores instead of 64 scattered b16 stores/thread.
// z=2 swaps operands (A=Wv, B=values) so the output is V^T directly.
// ---------------------------------------------------------------------------
#define ES_STRIDE 136   // shorts; 272 B: 16B-aligned rows, banks shift 4/row
__global__ __launch_bounds__(256, 3)
void proj(const float* __restrict__ Xq, const float* __restrict__ Xk,
          const float* __restrict__ Xv, const short* __restrict__ Wb,
          short* __restrict__ qb, short* __restrict__ kbuf,
          short* __restrict__ vt) {
    __shared__ __align__(16) char lds_raw[49152];
    float4* Fs = (float4*)lds_raw;             // [2][1024] fp32 tiles, 32 KB
    short8* Hs = (short8*)(lds_raw + 32768);   // [2][512] bf16 tiles, 16 KB
    short*  Es = (short*)lds_raw;              // epilogue 128 x 136, 34 KB

    const int L = blockIdx.x;
    const int xcd = L & 7, i = L >> 3;   // i 0..95
    const int z = i >> 5;                // 0..2
    const int m = i & 31;
    const int ty = xcd * 4 + (m & 3);    // 0..31  (X strip)
    const int tx = m >> 2;               // 0..7   (W strip)

    const float* Fop; const short* Hop; short* C;
    if (z == 0)      { Fop = Xq; Hop = Wb;           C = qb;   }
    else if (z == 1) { Fop = Xk; Hop = Wb + WE;      C = kbuf; }
    else             { Fop = Xv; Hop = Wb + 2 * WE;  C = vt;   }
    const int fr0 = ty * 128;   // X rows
    const int hr0 = tx * 128;   // W rows

    const int t = threadIdx.x, w = t >> 6, lane = t & 63;
    const int l15 = lane & 15, quad = lane >> 4;
    const int mh = (w >> 1) * 64, nh2 = (w & 1) * 64;

    auto stageF = [&](int p, int k0) {
#pragma unroll
        for (int j = 0; j < 4; ++j) {
            int g = j * 256 + t, row = g >> 3, c = g & 7;
            int cs = c ^ (row & 7);
            gload16(Fop + (size_t)(fr0 + row) * EMB + k0 + cs * 4,
                    &Fs[p * 1024 + j * 256 + w * 64]);
        }
    };
    auto stageH = [&](int p, int k0) {
#pragma unroll
        for (int j = 0; j < 2; ++j) {
            int g = j * 256 + t, row = g & 127, c = g >> 7;
            gload16(Hop + (size_t)(hr0 + row) * EMB + k0 + c * 8,
                    &Hs[p * 512 + j * 256 + w * 64]);
        }
    };
    auto fragF = [&](int p, int fr) -> short8 {
        int r7 = fr & 7;
        float4 a = Fs[p * 1024 + fr * 8 + ((2 * quad) ^ r7)];
        float4 b = Fs[p * 1024 + fr * 8 + ((2 * quad + 1) ^ r7)];
        return cvt8(a, b);
    };

    f32x4 acc[4][4];
#pragma unroll
    for (int a = 0; a < 4; ++a)
#pragma unroll
        for (int b = 0; b < 4; ++b) acc[a][b] = 0.f;

    stageF(0, 0);
    stageH(0, 0);

    int p = 0;
    for (int k0 = 0; k0 < EMB; k0 += 32, p ^= 1) {
        __syncthreads();   // drains buf-p loads (issued one full iter ago)
        if (k0 + 32 < EMB) { stageF(p ^ 1, k0 + 32); stageH(p ^ 1, k0 + 32); }

        short8 af[4], bf[4];
        if (z < 2) {   // A = X (fp32), B = W (bf16)
#pragma unroll
            for (int mi = 0; mi < 4; ++mi)
                af[mi] = fragF(p, mh + mi * 16 + l15);
#pragma unroll
            for (int ni = 0; ni < 4; ++ni)
                bf[ni] = Hs[p * 512 + quad * 128 + nh2 + ni * 16 + l15];
        } else {       // A = Wv (bf16), B = values (fp32)
#pragma unroll
            for (int mi = 0; mi < 4; ++mi)
                af[mi] = Hs[p * 512 + quad * 128 + mh + mi * 16 + l15];
#pragma unroll
            for (int ni = 0; ni < 4; ++ni)
                bf[ni] = fragF(p, nh2 + ni * 16 + l15);
        }
#pragma unroll
        for (int mi = 0; mi < 4; ++mi)
#pragma unroll
            for (int ni = 0; ni < 4; ++ni)
                acc[mi][ni] = __builtin_amdgcn_mfma_f32_16x16x32_bf16(
                    af[mi], bf[ni], acc[mi][ni], 0, 0, 0);
    }

    // ---- packed epilogue: acc -> LDS (bf16, transposed layout) -> global --
    __syncthreads();   // all frag reads of last tile done before Es overwrite
#pragma unroll
    for (int mi = 0; mi < 4; ++mi)
#pragma unroll
        for (int ni = 0; ni < 4; ++ni)
#pragma unroll
            for (int r = 0; r < 4; ++r) {
                int lr_ = mh + mi * 16 + quad * 4 + r;   // A-side local row
                int lc_ = nh2 + ni * 16 + l15;           // B-side local col
                Es[lr_ * ES_STRIDE + lc_] = f2bf(acc[mi][ni][r]);
            }
    __syncthreads();
    {
        int row = t >> 1, half = t & 1;
        const short* src = Es + row * ES_STRIDE + half * 64;
        short* dst;
        if (z < 2) {   // C[m][n]: m = fr0+row, n = hr0 + half*64 ..
            dst = C + (size_t)(fr0 + row) * EMB + hr0 + half * 64;
        } else {       // vt[b][d][s]: d = hr0+row, s-range = fr0..fr0+127
            int bz = fr0 >> 11, s0 = fr0 & 2047;
            dst = C + ((size_t)bz * EMB + hr0 + row) * SEQ + s0 + half * 64;
        }
#pragma unroll
        for (int j = 0; j < 8; ++j)
            *(short8*)(dst + j * 8) = *(const short8*)(src + j * 8);
    }
}

// ---------------------------------------------------------------------------
// Flash attention, bf16 MFMA, fixed-max softmax, S^T trick. NEW: 64-row
// q-tiles -> 1024 blocks, 40 KB LDS, 4 blocks/CU (16 waves). Wave owns 16
// q-rows. K/V double-buffer, one barrier/tile; P reuses the dead Q LDS.
// ---------------------------------------------------------------------------
__global__ __launch_bounds__(256, 4)
void attn_mfma(const short* __restrict__ Qg, const short* __restrict__ Kg,
               const short* __restrict__ Vtg, float* __restrict__ OutD) {
    __shared__ short8 QPs[512];     // Q [dchunk(8)][qrow(64)], then P; 8KB
    __shared__ short8 Ks[2][512];   // dbuf [dchunk(8)][krow(64)] 16KB
    __shared__ short8 Vs[2][512];   // dbuf [kchunk(8)][d(64)]    16KB

    const int t = threadIdx.x, w = t >> 6, lane = t & 63;
    const int l15 = lane & 15, quad = lane >> 4;
    const int L = blockIdx.x;
    const int xcd = L & 7, i = L >> 3;        // i 0..127
    const int bh = xcd * 4 + (i & 3);         // 0..31
    const int q0 = (i >> 2) * 64;             // 32 q-tiles
    const int b = bh >> 4, h = bh & 15;
    const short* Qb = Qg + (size_t)b * SEQ * EMB + h * HD;
    const short* Kb = Kg + (size_t)b * SEQ * EMB + h * HD;
    const short* Vb = Vtg + ((size_t)b * EMB + h * HD) * SEQ;

    // prologue: stage Q tile (64x64) + K/V tile0
#pragma unroll
    for (int j2 = 0; j2 < 2; ++j2) {
        int c = w * 2 + j2;
        gload16(Qb + (size_t)(q0 + lane) * EMB + c * 8, &QPs[c * 64]);
        gload16(Kb + (size_t)lane * EMB + c * 8, &Ks[0][c * 64]);
        gload16(Vb + (size_t)lane * SEQ + c * 8, &Vs[0][c * 64]);
    }
    __syncthreads();   // drains prologue loads

    // hoist Q fragments (B-operand, lane l15 = q). Wave reads only its own
    // 16 q-rows -- the same rows it later P-writes -> no extra barrier.
    short8 qf[2];
#pragma unroll
    for (int kb2 = 0; kb2 < 2; ++kb2)
        qf[kb2] = QPs[(kb2 * 4 + quad) * 64 + w * 16 + l15];

    f32x4 o[4];
    float lr = 0.f;
#pragma unroll
    for (int ni = 0; ni < 4; ++ni) o[ni] = 0.f;
    const float cl2 = 0.18033688011112042f;   // (1/8) * log2(e)
    const float c0  = 11.541560327111707f;    // 64 * cl2

    int p = 0;
    for (int kt = 0; kt < SEQ; kt += 64, p ^= 1) {
        if (kt) __syncthreads();   // drains buf-p loads (issued last iter)
        if (kt + 64 < SEQ) {
#pragma unroll
            for (int j2 = 0; j2 < 2; ++j2) {
                int c = w * 2 + j2;
                gload16(Kb + (size_t)(kt + 64 + lane) * EMB + c * 8,
                        &Ks[p ^ 1][c * 64]);
                gload16(Vb + (size_t)lane * SEQ + kt + 64 + c * 8,
                        &Vs[p ^ 1][c * 64]);
            }
        }

        // ---- T = K Q^T : rows = key (64), cols = q (wave's 16) ----
        f32x4 s[4];
#pragma unroll
        for (int kblk = 0; kblk < 4; ++kblk) s[kblk] = 0.f;
#pragma unroll
        for (int kb2 = 0; kb2 < 2; ++kb2) {
            short8 ak[4];
#pragma unroll
            for (int kblk = 0; kblk < 4; ++kblk)
                ak[kblk] = Ks[p][(kb2 * 4 + quad) * 64 + kblk * 16 + l15];
#pragma unroll
            for (int kblk = 0; kblk < 4; ++kblk)
                s[kblk] = __builtin_amdgcn_mfma_f32_16x16x32_bf16(
                    ak[kblk], qf[kb2], s[kblk], 0, 0, 0);
        }

        // ---- fixed-max softmax + packed b64 P write (into QPs) ----
        {
            int row = w * 16 + l15;   // q row (lane l15 = q)
#pragma unroll
            for (int kblk = 0; kblk < 4; ++kblk) {
                float p0 = __builtin_amdgcn_exp2f(fmaf(s[kblk][0], cl2, -c0));
                float p1 = __builtin_amdgcn_exp2f(fmaf(s[kblk][1], cl2, -c0));
                float p2 = __builtin_amdgcn_exp2f(fmaf(s[kblk][2], cl2, -c0));
                float p3 = __builtin_amdgcn_exp2f(fmaf(s[kblk][3], cl2, -c0));
                lr += (p0 + p1) + (p2 + p3);
                uint2 pv; pv.x = pk2(p0, p1); pv.y = pk2(p2, p3);
                int chunk = kblk * 2 + (quad >> 1);
                *(uint2*)((char*)QPs +
                          (((chunk * 64 + row) << 4) | ((quad & 1) << 3))) = pv;
            }
        }
        // no barrier: wave reads back only its own q rows (same-wave RAW)

        // ---- O += P V ----
#pragma unroll
        for (int kb2 = 0; kb2 < 2; ++kb2) {
            short8 ap = QPs[(kb2 * 4 + quad) * 64 + w * 16 + l15];
            short8 bv[4];
#pragma unroll
            for (int ni = 0; ni < 4; ++ni)
                bv[ni] = Vs[p][(kb2 * 4 + quad) * 64 + ni * 16 + l15];
#pragma unroll
            for (int ni = 0; ni < 4; ++ni)
                o[ni] = __builtin_amdgcn_mfma_f32_16x16x32_bf16(
                    ap, bv[ni], o[ni], 0, 0, 0);
        }
    }

    // ---- epilogue: reduce l across quads, normalize, store fp32 ----
    lr += __shfl_xor(lr, 16);
    lr += __shfl_xor(lr, 32);
#pragma unroll
    for (int r = 0; r < 4; ++r) {
        float inv = 1.0f / __shfl(lr, quad * 4 + r);
        int q = q0 + w * 16 + quad * 4 + r;
        float* op = OutD + ((size_t)b * SEQ + q) * EMB + h * HD;
#pragma unroll
        for (int ni = 0; ni < 4; ++ni)
            op[ni * 16 + l15] = o[ni][r] * inv;
    }
}

// ---------------------------------------------------------------------------
extern "C" void kernel_launch(void* const* d_in, const int* in_sizes, int n_in,
                              void* d_out, int out_size, void* d_ws, size_t ws_size,
                              hipStream_t stream) {
    const float* values  = (const float*)d_in[0];
    const float* keys    = (const float*)d_in[1];
    const float* queries = (const float*)d_in[2];
    const float* Wv      = (const float*)d_in[3];
    const float* Wk      = (const float*)d_in[4];
    const float* Wq      = (const float*)d_in[5];
    float* out = (float*)d_out;

    // ws: qb, kb, vt (8MB each) + wb = [Wq|Wk|Wv] bf16 (6MB) = 30MB
    short* qb = (short*)d_ws;
    short* kb = qb + XE;
    short* vt = kb + XE;
    short* wb = vt + XE;

    cvt_w<<<1536, 256, 0, stream>>>(Wq, Wk, Wv, wb);
    proj<<<768, 256, 0, stream>>>(queries, keys, values, wb, qb, kb, vt);
    attn_mfma<<<1024, 256, 0, stream>>>(qb, kb, vt, out);
}

// Round 8
// 208.828 us; speedup vs baseline: 1.1077x; 1.1077x over previous
//
#include <hip/hip_runtime.h>
#include <math.h>

#define SEQ 2048
#define EMB 1024
#define NH  16
#define HD  64

typedef __attribute__((ext_vector_type(8))) short short8;   // 8 bf16 = 4 VGPRs
typedef __attribute__((ext_vector_type(4))) float f32x4;    // MFMA acc

static const size_t XE = (size_t)2 * SEQ * EMB;  // 4,194,304 elems
static const size_t WE = (size_t)EMB * EMB;      // 1,048,576 elems

// RNE float -> bf16 bits (inputs finite)
static __device__ __forceinline__ short f2bf(float f) {
    unsigned u = __builtin_bit_cast(unsigned, f);
    u = u + 0x7fffu + ((u >> 16) & 1u);
    return (short)(u >> 16);
}

#if __has_builtin(__builtin_amdgcn_cvt_pk_bf16_f32)
typedef __attribute__((ext_vector_type(2))) __bf16 bf16x2;
static __device__ __forceinline__ unsigned pk2(float a, float b) {
    bf16x2 v = __builtin_amdgcn_cvt_pk_bf16_f32(a, b);
    return __builtin_bit_cast(unsigned, v);
}
#else
static __device__ __forceinline__ unsigned pk2(float a, float b) {
    return (unsigned)(unsigned short)f2bf(a) |
           ((unsigned)(unsigned short)f2bf(b) << 16);
}
#endif

static __device__ __forceinline__ short8 cvt8(float4 a, float4 b) {
    union { unsigned u[4]; short8 s; } r;
    r.u[0] = pk2(a.x, a.y); r.u[1] = pk2(a.z, a.w);
    r.u[2] = pk2(b.x, b.y); r.u[3] = pk2(b.z, b.w);
    return r.s;
}

// async global->LDS, 16B/lane; LDS dest = wave-uniform base + lane*16
static __device__ __forceinline__ void gload16(const void* g, void* l) {
    __builtin_amdgcn_global_load_lds(
        (const __attribute__((address_space(1))) void*)g,
        (__attribute__((address_space(3))) void*)l, 16, 0, 0);
}

// ---------------------------------------------------------------------------
// Convert the three weight matrices to bf16: dst = [Wq | Wk | Wv].
// ---------------------------------------------------------------------------
__global__ __launch_bounds__(256)
void cvt_w(const float* __restrict__ s0, const float* __restrict__ s1,
           const float* __restrict__ s2, short* __restrict__ d) {
    int id = blockIdx.x;                 // 0..1535
    int seg = id >> 9, off = id & 511;
    const float* s = (seg == 0) ? s0 : (seg == 1) ? s1 : s2;
    short* dd = d + (size_t)seg * WE;
    size_t i = (size_t)off * 256 + threadIdx.x;
    const float4* sp = (const float4*)s;
    float4 a = sp[2 * i], b = sp[2 * i + 1];
    *(short8*)(dd + i * 8) = cvt8(a, b);
}

// ---------------------------------------------------------------------------
// Projection GEMM (unchanged from round 6; 69 us known-good).
// ---------------------------------------------------------------------------
#define ES_STRIDE 136
__global__ __launch_bounds__(256, 3)
void proj(const float* __restrict__ Xq, const float* __restrict__ Xk,
          const float* __restrict__ Xv, const short* __restrict__ Wb,
          short* __restrict__ qb, short* __restrict__ kbuf,
          short* __restrict__ vt) {
    __shared__ __align__(16) char lds_raw[49152];
    float4* Fs = (float4*)lds_raw;             // [2][1024] fp32 tiles, 32 KB
    short8* Hs = (short8*)(lds_raw + 32768);   // [2][512] bf16 tiles, 16 KB
    short*  Es = (short*)lds_raw;              // epilogue 128 x 136, 34 KB

    const int L = blockIdx.x;
    const int xcd = L & 7, i = L >> 3;   // i 0..95
    const int z = i >> 5;                // 0..2
    const int m = i & 31;
    const int ty = xcd * 4 + (m & 3);    // 0..31  (X strip)
    const int tx = m >> 2;               // 0..7   (W strip)

    const float* Fop; const short* Hop; short* C;
    if (z == 0)      { Fop = Xq; Hop = Wb;           C = qb;   }
    else if (z == 1) { Fop = Xk; Hop = Wb + WE;      C = kbuf; }
    else             { Fop = Xv; Hop = Wb + 2 * WE;  C = vt;   }
    const int fr0 = ty * 128;   // X rows
    const int hr0 = tx * 128;   // W rows

    const int t = threadIdx.x, w = t >> 6, lane = t & 63;
    const int l15 = lane & 15, quad = lane >> 4;
    const int mh = (w >> 1) * 64, nh2 = (w & 1) * 64;

    auto stageF = [&](int p, int k0) {
#pragma unroll
        for (int j = 0; j < 4; ++j) {
            int g = j * 256 + t, row = g >> 3, c = g & 7;
            int cs = c ^ (row & 7);
            gload16(Fop + (size_t)(fr0 + row) * EMB + k0 + cs * 4,
                    &Fs[p * 1024 + j * 256 + w * 64]);
        }
    };
    auto stageH = [&](int p, int k0) {
#pragma unroll
        for (int j = 0; j < 2; ++j) {
            int g = j * 256 + t, row = g & 127, c = g >> 7;
            gload16(Hop + (size_t)(hr0 + row) * EMB + k0 + c * 8,
                    &Hs[p * 512 + j * 256 + w * 64]);
        }
    };
    auto fragF = [&](int p, int fr) -> short8 {
        int r7 = fr & 7;
        float4 a = Fs[p * 1024 + fr * 8 + ((2 * quad) ^ r7)];
        float4 b = Fs[p * 1024 + fr * 8 + ((2 * quad + 1) ^ r7)];
        return cvt8(a, b);
    };

    f32x4 acc[4][4];
#pragma unroll
    for (int a = 0; a < 4; ++a)
#pragma unroll
        for (int b = 0; b < 4; ++b) acc[a][b] = 0.f;

    stageF(0, 0);
    stageH(0, 0);

    int p = 0;
    for (int k0 = 0; k0 < EMB; k0 += 32, p ^= 1) {
        __syncthreads();
        if (k0 + 32 < EMB) { stageF(p ^ 1, k0 + 32); stageH(p ^ 1, k0 + 32); }

        short8 af[4], bf[4];
        if (z < 2) {
#pragma unroll
            for (int mi = 0; mi < 4; ++mi)
                af[mi] = fragF(p, mh + mi * 16 + l15);
#pragma unroll
            for (int ni = 0; ni < 4; ++ni)
                bf[ni] = Hs[p * 512 + quad * 128 + nh2 + ni * 16 + l15];
        } else {
#pragma unroll
            for (int mi = 0; mi < 4; ++mi)
                af[mi] = Hs[p * 512 + quad * 128 + mh + mi * 16 + l15];
#pragma unroll
            for (int ni = 0; ni < 4; ++ni)
                bf[ni] = fragF(p, nh2 + ni * 16 + l15);
        }
#pragma unroll
        for (int mi = 0; mi < 4; ++mi)
#pragma unroll
            for (int ni = 0; ni < 4; ++ni)
                acc[mi][ni] = __builtin_amdgcn_mfma_f32_16x16x32_bf16(
                    af[mi], bf[ni], acc[mi][ni], 0, 0, 0);
    }

    __syncthreads();
#pragma unroll
    for (int mi = 0; mi < 4; ++mi)
#pragma unroll
        for (int ni = 0; ni < 4; ++ni)
#pragma unroll
            for (int r = 0; r < 4; ++r) {
                int lr_ = mh + mi * 16 + quad * 4 + r;
                int lc_ = nh2 + ni * 16 + l15;
                Es[lr_ * ES_STRIDE + lc_] = f2bf(acc[mi][ni][r]);
            }
    __syncthreads();
    {
        int row = t >> 1, half = t & 1;
        const short* src = Es + row * ES_STRIDE + half * 64;
        short* dst;
        if (z < 2) {
            dst = C + (size_t)(fr0 + row) * EMB + hr0 + half * 64;
        } else {
            int bz = fr0 >> 11, s0 = fr0 & 2047;
            dst = C + ((size_t)bz * EMB + hr0 + row) * SEQ + s0 + half * 64;
        }
#pragma unroll
        for (int j = 0; j < 8; ++j)
            *(short8*)(dst + j * 8) = *(const short8*)(src + j * 8);
    }
}

// ---------------------------------------------------------------------------
// Flash attention, bf16 MFMA, fixed-max softmax, S^T trick. Round-6 shape
// (128-q block, wave owns 32 q) with: (a) KT=128 double-period -- two 64-key
// sub-tiles per barrier sharing one P buffer (barriers 32 -> 16); (b) fully
// coalesced XOR-swizzled staging: every gload16 reads 8 rows x 128B
// contiguous; slot(row,c) = row*8 + (c ^ (row&7)) everywhere -> frag reads
// <=2-way banked. LDS 80KB -> 2 blocks/CU (same effective occupancy as r6).
// ---------------------------------------------------------------------------
__global__ __launch_bounds__(256, 2)
void attn_mfma(const short* __restrict__ Qg, const short* __restrict__ Kg,
               const short* __restrict__ Vtg, float* __restrict__ OutD) {
    __shared__ short8 QPs[1024];     // Q then P: [row(128)][c(8)^] 16KB
    __shared__ short8 Ks[2][1024];   // dbuf [krow(128)][dchunk(8)^] 32KB
    __shared__ short8 Vs[2][1024];   // dbuf [half(2)][drow(64)][kc(8)^] 32KB

    const int t = threadIdx.x, w = t >> 6, lane = t & 63;
    const int l15 = lane & 15, quad = lane >> 4;
    const int lr3 = lane >> 3, lc7 = lane & 7;   // staging row/chunk split
    const int L = blockIdx.x;
    const int xcd = L & 7, i = L >> 3;        // i 0..63
    const int bh = xcd * 4 + (i & 3);         // 0..31
    const int q0 = (i >> 2) * 128;            // 16 q-tiles
    const int b = bh >> 4, h = bh & 15;
    const short* Qb = Qg + (size_t)b * SEQ * EMB + h * HD;
    const short* Kb = Kg + (size_t)b * SEQ * EMB + h * HD;
    const short* Vb = Vtg + ((size_t)b * EMB + h * HD) * SEQ;

    // staging: one gload16 = 8 rows x 128B coalesced, XOR placement
    auto stageKV = [&](int p, int kt) {
#pragma unroll
        for (int j = 0; j < 4; ++j) {
            int rb = w * 32 + j * 8;                 // K key-rows
            int krow = rb + lr3;
            gload16(Kb + (size_t)(kt + krow) * EMB + ((lc7 ^ (krow & 7)) * 8),
                    &Ks[p][rb * 8]);
            int half = w >> 1, db = (w & 1) * 32 + j * 8;   // V d-rows
            int d = db + lr3;
            gload16(Vb + (size_t)d * SEQ + kt + half * 64 + ((lc7 ^ (d & 7)) * 8),
                    &Vs[p][half * 512 + db * 8]);
        }
    };

    // prologue: Q tile + period 0
#pragma unroll
    for (int j = 0; j < 4; ++j) {
        int rb = w * 32 + j * 8;
        int row = rb + lr3;
        gload16(Qb + (size_t)(q0 + row) * EMB + ((lc7 ^ (row & 7)) * 8),
                &QPs[rb * 8]);
    }
    stageKV(0, 0);
    __syncthreads();   // drains prologue loads

    // hoist Q fragments (B-operand, lane l15 = q); wave-private rows, so no
    // barrier needed before P reuses this region.
    short8 qf[2][2];
#pragma unroll
    for (int qi = 0; qi < 2; ++qi)
#pragma unroll
        for (int kb2 = 0; kb2 < 2; ++kb2) {
            int row = w * 32 + qi * 16 + l15;
            qf[qi][kb2] = QPs[row * 8 + ((kb2 * 4 + quad) ^ (l15 & 7))];
        }

    f32x4 o[2][4];
    float lr[2] = {0.f, 0.f};
#pragma unroll
    for (int qi = 0; qi < 2; ++qi)
#pragma unroll
        for (int ni = 0; ni < 4; ++ni) o[qi][ni] = 0.f;
    const float cl2 = 0.18033688011112042f;   // (1/8) * log2(e)
    const float c0  = 11.541560327111707f;    // 64 * cl2

    int p = 0;
    for (int kt = 0; kt < SEQ; kt += 128, p ^= 1) {
        if (kt) __syncthreads();   // drains buf-p loads (issued last period)
        if (kt + 128 < SEQ) stageKV(p ^ 1, kt + 128);

#pragma unroll
        for (int half = 0; half < 2; ++half) {
            // ---- T = K Q^T : rows = key (64 of this half), cols = q ----
            f32x4 s[4][2];
#pragma unroll
            for (int kblk = 0; kblk < 4; ++kblk)
#pragma unroll
                for (int qi = 0; qi < 2; ++qi) s[kblk][qi] = 0.f;
#pragma unroll
            for (int kb2 = 0; kb2 < 2; ++kb2) {
                short8 ak[4];
#pragma unroll
                for (int kblk = 0; kblk < 4; ++kblk) {
                    int row = half * 64 + kblk * 16 + l15;
                    ak[kblk] = Ks[p][row * 8 + ((kb2 * 4 + quad) ^ (l15 & 7))];
                }
#pragma unroll
                for (int kblk = 0; kblk < 4; ++kblk)
#pragma unroll
                    for (int qi = 0; qi < 2; ++qi)
                        s[kblk][qi] = __builtin_amdgcn_mfma_f32_16x16x32_bf16(
                            ak[kblk], qf[qi][kb2], s[kblk][qi], 0, 0, 0);
            }

            // ---- fixed-max softmax + packed b64 P write ----
#pragma unroll
            for (int qi = 0; qi < 2; ++qi) {
                int row = w * 32 + qi * 16 + l15;
#pragma unroll
                for (int kblk = 0; kblk < 4; ++kblk) {
                    float p0 = __builtin_amdgcn_exp2f(fmaf(s[kblk][qi][0], cl2, -c0));
                    float p1 = __builtin_amdgcn_exp2f(fmaf(s[kblk][qi][1], cl2, -c0));
                    float p2 = __builtin_amdgcn_exp2f(fmaf(s[kblk][qi][2], cl2, -c0));
                    float p3 = __builtin_amdgcn_exp2f(fmaf(s[kblk][qi][3], cl2, -c0));
                    lr[qi] += (p0 + p1) + (p2 + p3);
                    uint2 pv; pv.x = pk2(p0, p1); pv.y = pk2(p2, p3);
                    int kc = kblk * 2 + (quad >> 1);
                    *(uint2*)((char*)QPs +
                        (((row * 8 + (kc ^ (l15 & 7))) << 4) | ((quad & 1) << 3)))
                        = pv;
                }
            }
            // no barrier: wave reads back only its own q rows (same-wave RAW)

            // ---- O += P V ----
#pragma unroll
            for (int kb2 = 0; kb2 < 2; ++kb2) {
                short8 ap[2], bv[4];
#pragma unroll
                for (int qi = 0; qi < 2; ++qi) {
                    int row = w * 32 + qi * 16 + l15;
                    ap[qi] = QPs[row * 8 + ((kb2 * 4 + quad) ^ (l15 & 7))];
                }
#pragma unroll
                for (int ni = 0; ni < 4; ++ni) {
                    int dr = ni * 16 + l15;
                    bv[ni] = Vs[p][half * 512 + dr * 8 +
                                   ((kb2 * 4 + quad) ^ (l15 & 7))];
                }
#pragma unroll
                for (int qi = 0; qi < 2; ++qi)
#pragma unroll
                    for (int ni = 0; ni < 4; ++ni)
                        o[qi][ni] = __builtin_amdgcn_mfma_f32_16x16x32_bf16(
                            ap[qi], bv[ni], o[qi][ni], 0, 0, 0);
            }
        }
    }

    // ---- epilogue: reduce l across quads, normalize, store fp32 ----
#pragma unroll
    for (int qi = 0; qi < 2; ++qi) {
        float l = lr[qi];
        l += __shfl_xor(l, 16);
        l += __shfl_xor(l, 32);
        lr[qi] = l;
    }
#pragma unroll
    for (int qi = 0; qi < 2; ++qi)
#pragma unroll
        for (int r = 0; r < 4; ++r) {
            float inv = 1.0f / __shfl(lr[qi], quad * 4 + r);
            int q = q0 + w * 32 + qi * 16 + quad * 4 + r;
            float* op = OutD + ((size_t)b * SEQ + q) * EMB + h * HD;
#pragma unroll
            for (int ni = 0; ni < 4; ++ni)
                op[ni * 16 + l15] = o[qi][ni][r] * inv;
        }
}

// ---------------------------------------------------------------------------
extern "C" void kernel_launch(void* const* d_in, const int* in_sizes, int n_in,
                              void* d_out, int out_size, void* d_ws, size_t ws_size,
                              hipStream_t stream) {
    const float* values  = (const float*)d_in[0];
    const float* keys    = (const float*)d_in[1];
    const float* queries = (const float*)d_in[2];
    const float* Wv      = (const float*)d_in[3];
    const float* Wk      = (const float*)d_in[4];
    const float* Wq      = (const float*)d_in[5];
    float* out = (float*)d_out;

    // ws: qb, kb, vt (8MB each) + wb = [Wq|Wk|Wv] bf16 (6MB) = 30MB
    short* qb = (short*)d_ws;
    short* kb = qb + XE;
    short* vt = kb + XE;
    short* wb = vt + XE;

    cvt_w<<<1536, 256, 0, stream>>>(Wq, Wk, Wv, wb);
    proj<<<768, 256, 0, stream>>>(queries, keys, values, wb, qb, kb, vt);
    attn_mfma<<<512, 256, 0, stream>>>(qb, kb, vt, out);
}